// Round 8
// baseline (99.185 us; speedup 1.0000x reference)
//
#include <hip/hip_runtime.h>
#include <hip/hip_bf16.h>
#include <cstdint>

#define B_TOT  2048
#define N_NODE 64
#define D_IN   256
#define D_OUT  256
#define N_TYPE 8

typedef __attribute__((ext_vector_type(8))) short bf16x8;
typedef __attribute__((ext_vector_type(4))) float f32x4;
typedef unsigned short u16;

__device__ __forceinline__ u16 f2bf(float f) {
  union { float f; unsigned u; } v; v.f = f;
  unsigned r = v.u + 0x7FFFu + ((v.u >> 16) & 1u);   // round-to-nearest-even
  return (u16)(r >> 16);
}

__device__ __forceinline__ bf16x8 cvt8(float4 a, float4 b) {
  bf16x8 r;
  r[0] = (short)f2bf(a.x); r[1] = (short)f2bf(a.y);
  r[2] = (short)f2bf(a.z); r[3] = (short)f2bf(a.w);
  r[4] = (short)f2bf(b.x); r[5] = (short)f2bf(b.y);
  r[6] = (short)f2bf(b.z); r[7] = (short)f2bf(b.w);
  return r;
}

#define GLDS(SRC, DST) __builtin_amdgcn_global_load_lds( \
    (const __attribute__((address_space(1))) unsigned int*)(SRC), \
    (__attribute__((address_space(3))) unsigned int*)(DST), 16, 0, 0)

// ---- prep: W image in MFMA-fragment order + G image (bf16) ------------------
// W image: ws[ty*65536 + c*8192 + o*32 + kl]  (u16), kl = k&31, c = k>>5.
__global__ __launch_bounds__(256)
void prep_kernel(const float* __restrict__ w, const float* __restrict__ G,
                 u16* __restrict__ ws)
{
  int e = blockIdx.x * 256 + threadIdx.x;
  if (e < N_TYPE * D_OUT * D_IN) {
    int ty = e >> 16, o = (e >> 8) & 255, k = e & 255;
    int c = k >> 5, kl = k & 31;
    ws[(size_t)ty * 65536 + c * 8192 + o * 32 + kl] = f2bf(w[e]);
  } else if (e < N_TYPE * D_OUT * D_IN + N_NODE * N_NODE) {
    int g = e - N_TYPE * D_OUT * D_IN;
    int m = g >> 6, n = g & 63;
    int s = (n >> 5) * 4 + ((n >> 2) & 3);
    int j = ((n >> 4) & 1) * 4 + (n & 3);
    ws[524288 + (size_t)(m * 8 + (s ^ (m & 7))) * 8 + j] = f2bf(G[g]);
  }
}

// ---- Kernel A: h[b][n][o] = sum_i W[type[n]][o][i] * x[b][n][i] -------------
// Round-4-proven structure, halved tile: 32 batches x 256 out per block, one
// node; 4 waves; x tile (32KB fp32) staged via global_load_lds; ONE
// __syncthreads (drains DMA); compute from LDS + L2-hot W image.
// 32KB LDS + cap 128 VGPR -> 4 blocks/CU: 4-way stage/compute overlap.
__global__ __launch_bounds__(256, 4)
void pernode_gemm(const float* __restrict__ x, const u16* __restrict__ wimg,
                  const int* __restrict__ types, u16* __restrict__ hout)
{
  const int node  = blockIdx.x & 63;
  const int btile = blockIdx.x >> 6;
  const int b0 = btile * 32;
  const int t = threadIdx.x;
  const int lane = t & 63, wid = t >> 6;
  const int l15 = lane & 15, lk = lane >> 4;
  const int o0 = wid * 64;                    // wave's o-tile (4 frags)

  __shared__ alignas(16) float xs[32][256];   // 32KB; unit p of row r = src unit p^r

  const int ty = types[node];

  #pragma unroll
  for (int j = 0; j < 8; ++j) {
    const int r = wid * 8 + j;
    const float* src = x + ((size_t)(b0 + r) * N_NODE + node) * D_IN + ((lane ^ r) << 2);
    GLDS(src, &xs[r][0]);
  }
  __syncthreads();

  f32x4 acc[4][2];   // [mf: o-frag][nb: b-frag]
  #pragma unroll
  for (int i = 0; i < 4; ++i)
    #pragma unroll
    for (int j = 0; j < 2; ++j) acc[i][j] = (f32x4){0.f, 0.f, 0.f, 0.f};

  const u16* wbp = wimg + (size_t)ty * 65536 + (size_t)(o0 + l15) * 32 + lk * 8;

  #pragma unroll
  for (int c = 0; c < 8; ++c) {
    bf16x8 wf[4];
    #pragma unroll
    for (int mf = 0; mf < 4; ++mf)
      wf[mf] = *(const bf16x8*)(wbp + c * 8192 + mf * 512);
    bf16x8 xf[2];
    #pragma unroll
    for (int nb = 0; nb < 2; ++nb) {
      const int r = nb * 16 + l15;
      const int u0 = c * 8 + lk * 2;
      float4 lo = *(const float4*)&xs[r][(u0 ^ r) << 2];
      float4 hi = *(const float4*)&xs[r][((u0 + 1) ^ r) << 2];
      xf[nb] = cvt8(lo, hi);
    }
    #pragma unroll
    for (int nb = 0; nb < 2; ++nb)
      #pragma unroll
      for (int mf = 0; mf < 4; ++mf)
        acc[mf][nb] = __builtin_amdgcn_mfma_f32_16x16x32_bf16(wf[mf], xf[nb], acc[mf][nb], 0, 0, 0);
  }

  // D frag: row(o) = o0 + mf*16 + lk*4 + rr (contiguous), col(b) = b0 + nb*16 + l15
  #pragma unroll
  for (int nb = 0; nb < 2; ++nb) {
    u16* hp = hout + (size_t)(b0 + nb * 16 + l15) * 32768 + node * 256 + o0 + lk * 4;
    #pragma unroll
    for (int mf = 0; mf < 4; ++mf) {
      ushort4 pv = { f2bf(acc[mf][nb][0]), f2bf(acc[mf][nb][1]),
                     f2bf(acc[mf][nb][2]), f2bf(acc[mf][nb][3]) };
      *(ushort4*)(hp + mf * 16) = pv;
    }
  }
}

// ---- Kernel B: out[b][m][o] = sum_n G[m][n]*h[b][n][o] + bias[o], MFMA, in-place
__global__ __launch_bounds__(256)
void graph_mix(const u16* __restrict__ gimg, const float* __restrict__ bias,
               float* __restrict__ out)
{
  const int b = blockIdx.x;
  const int t = threadIdx.x;
  const int lane = t & 63, wid = t >> 6, l15 = lane & 15, lk = lane >> 4;

  __shared__ u16 himg[16384];   // [n][o] bf16, linear
  __shared__ u16 gl[4096];      // G image (perm+swizzle baked by prep)

  const u16* hsrc = (const u16*)((const char*)out + (size_t)b * 65536);
  bf16x8 hv[8], gv[2];
  #pragma unroll
  for (int i = 0; i < 8; ++i) hv[i] = *(const bf16x8*)(hsrc + t * 64 + i * 8);
  #pragma unroll
  for (int i = 0; i < 2; ++i) gv[i] = *(const bf16x8*)(gimg + t * 16 + i * 8);
  float bb[4];
  #pragma unroll
  for (int nt = 0; nt < 4; ++nt) bb[nt] = bias[wid * 64 + nt * 16 + l15];
  #pragma unroll
  for (int i = 0; i < 8; ++i) *(bf16x8*)&himg[t * 64 + i * 8] = hv[i];
  #pragma unroll
  for (int i = 0; i < 2; ++i) *(bf16x8*)&gl[t * 16 + i * 8] = gv[i];
  __syncthreads();   // drains vmcnt: all global h reads complete before any out write

  f32x4 acc[4][4];
  #pragma unroll
  for (int i = 0; i < 4; ++i)
    #pragma unroll
    for (int j = 0; j < 4; ++j) acc[i][j] = (f32x4){0.f, 0.f, 0.f, 0.f};

  #pragma unroll
  for (int ks = 0; ks < 2; ++ks) {
    bf16x8 ag[4];
    #pragma unroll
    for (int mt = 0; mt < 4; ++mt) {
      int row = mt * 16 + l15;
      ag[mt] = *(const bf16x8*)&gl[(size_t)row * 64 + (size_t)((ks * 4 + lk) ^ (row & 7)) * 8];
    }
    #pragma unroll
    for (int nt = 0; nt < 4; ++nt) {
      int o = wid * 64 + nt * 16 + l15;
      bf16x8 bh;
      #pragma unroll
      for (int j = 0; j < 8; ++j) {   // gather h with the same k-perm as G's image
        int nk = ks * 32 + lk * 4 + (j & 3) + ((j >> 2) << 4);
        bh[j] = (short)himg[nk * 256 + o];
      }
      #pragma unroll
      for (int mt = 0; mt < 4; ++mt)
        acc[mt][nt] = __builtin_amdgcn_mfma_f32_16x16x32_bf16(ag[mt], bh, acc[mt][nt], 0, 0, 0);
    }
  }
  float* ob = out + (size_t)b * 16384;
  #pragma unroll
  for (int mt = 0; mt < 4; ++mt)
    #pragma unroll
    for (int nt = 0; nt < 4; ++nt)
      #pragma unroll
      for (int rr = 0; rr < 4; ++rr) {
        int m = mt * 16 + lk * 4 + rr;
        int o = wid * 64 + nt * 16 + l15;
        ob[(size_t)m * 256 + o] = acc[mt][nt][rr] + bb[nt];
      }
}

// ---- fallback (round-1, passing) — used only if ws_size is too small --------
__global__ __launch_bounds__(256)
void pernode_gemm_fb(const float* __restrict__ x, const float* __restrict__ w,
                     const int* __restrict__ types, float* __restrict__ h)
{
  const int node = blockIdx.y;
  const int b0   = blockIdx.x * 64;
  const int t    = threadIdx.x;
  const int lane = t & 63;
  const int wid  = t >> 6;
  const int wm   = wid >> 1;
  const int wn   = wid & 1;
  const int l15  = lane & 15;
  const int lk   = lane >> 4;

  __shared__ alignas(16) u16 xs[64][72];
  __shared__ alignas(16) u16 wsm[256][72];

  const int ty = types[node];
  const float* wb = w + (size_t)ty * (D_OUT * D_IN);
  const float* xb = x + ((size_t)b0 * N_NODE + node) * D_IN;

  f32x4 acc[2][8];
  #pragma unroll
  for (int i = 0; i < 2; ++i)
    #pragma unroll
    for (int j = 0; j < 8; ++j) acc[i][j] = (f32x4){0.f,0.f,0.f,0.f};

  const int cg = t & 15, r0 = t >> 4, c = cg * 4;
  const int dst = (c >> 5) * 32 + ((c >> 2) & 3) * 8 + ((c >> 4) & 1) * 4;

  for (int kc = 0; kc < 4; ++kc) {
    const int k0 = kc * 64;
    #pragma unroll
    for (int p = 0; p < 4; ++p) {
      const int row = r0 + p * 16;
      const float4 v = *(const float4*)(xb + (size_t)row * (N_NODE * D_IN) + k0 + c);
      ushort4 bv = { f2bf(v.x), f2bf(v.y), f2bf(v.z), f2bf(v.w) };
      *(ushort4*)&xs[row][dst] = bv;
    }
    #pragma unroll
    for (int p = 0; p < 16; ++p) {
      const int row = r0 + p * 16;
      const float4 v = *(const float4*)(wb + (size_t)row * D_IN + k0 + c);
      ushort4 bv = { f2bf(v.x), f2bf(v.y), f2bf(v.z), f2bf(v.w) };
      *(ushort4*)&wsm[row][dst] = bv;
    }
    __syncthreads();
    #pragma unroll
    for (int ks = 0; ks < 2; ++ks) {
      bf16x8 af[2], bfv[8];
      #pragma unroll
      for (int tm = 0; tm < 2; ++tm)
        af[tm] = *(const bf16x8*)&xs[wm*32 + tm*16 + l15][ks*32 + lk*8];
      #pragma unroll
      for (int tn = 0; tn < 8; ++tn)
        bfv[tn] = *(const bf16x8*)&wsm[wn*128 + tn*16 + l15][ks*32 + lk*8];
      #pragma unroll
      for (int tm = 0; tm < 2; ++tm)
        #pragma unroll
        for (int tn = 0; tn < 8; ++tn)
          acc[tm][tn] = __builtin_amdgcn_mfma_f32_16x16x32_bf16(af[tm], bfv[tn], acc[tm][tn], 0, 0, 0);
    }
    __syncthreads();
  }
  #pragma unroll
  for (int tm = 0; tm < 2; ++tm)
    #pragma unroll
    for (int tn = 0; tn < 8; ++tn)
      #pragma unroll
      for (int rr = 0; rr < 4; ++rr) {
        const int bb2 = b0 + wm*32 + tm*16 + lk*4 + rr;
        const int oo  = wn*128 + tn*16 + l15;
        h[((size_t)bb2 * N_NODE + node) * D_OUT + oo] = acc[tm][tn][rr];
      }
}

__global__ __launch_bounds__(256)
void graph_mix_fb(const float* __restrict__ G, const float* __restrict__ bias,
                  float* __restrict__ hb)
{
  const int b = blockIdx.x;
  const int t = threadIdx.x;
  float* base = hb + (size_t)b * (N_NODE * D_OUT);
  float hreg[N_NODE];
  #pragma unroll
  for (int n = 0; n < N_NODE; ++n) hreg[n] = base[(size_t)n * D_OUT + t];
  const float bv = bias[t];
  for (int m = 0; m < N_NODE; ++m) {
    const float* gr = G + m * N_NODE;
    float a0 = 0.f, a1 = 0.f, a2 = 0.f, a3 = 0.f;
    #pragma unroll
    for (int n = 0; n < N_NODE; n += 4) {
      a0 += gr[n]     * hreg[n];
      a1 += gr[n + 1] * hreg[n + 1];
      a2 += gr[n + 2] * hreg[n + 2];
      a3 += gr[n + 3] * hreg[n + 3];
    }
    base[(size_t)m * D_OUT + t] = (a0 + a1) + (a2 + a3) + bv;
  }
}

extern "C" void kernel_launch(void* const* d_in, const int* in_sizes, int n_in,
                              void* d_out, int out_size, void* d_ws, size_t ws_size,
                              hipStream_t stream) {
  const float* x     = (const float*)d_in[0];
  const float* G     = (const float*)d_in[1];
  const float* w     = (const float*)d_in[2];
  const float* bias  = (const float*)d_in[3];
  const int*   types = (const int*)d_in[4];

  const size_t WS_NEED = (size_t)(524288 + 4096) * 2;   // W img 1MB + G img 8KB
  if (ws_size >= WS_NEED) {
    u16* ws = (u16*)d_ws;
    prep_kernel<<<2064, 256, 0, stream>>>(w, G, ws);
    pernode_gemm<<<4096, 256, 0, stream>>>(x, ws, types, (u16*)d_out);
    graph_mix<<<2048, 256, 0, stream>>>(ws + 524288, bias, (float*)d_out);
  } else {
    dim3 gA(B_TOT / 64, N_NODE);
    pernode_gemm_fb<<<gA, 256, 0, stream>>>(x, w, types, (float*)d_out);
    graph_mix_fb<<<B_TOT, 256, 0, stream>>>(G, bias, (float*)d_out);
  }
}

// Round 9
// 96.106 us; speedup vs baseline: 1.0320x; 1.0320x over previous
//
#include <hip/hip_runtime.h>
#include <hip/hip_bf16.h>
#include <cstdint>

#define B_TOT  2048
#define N_NODE 64
#define D_IN   256
#define D_OUT  256
#define N_TYPE 8

typedef __attribute__((ext_vector_type(8))) short bf16x8;
typedef __attribute__((ext_vector_type(4))) float f32x4;
typedef unsigned short u16;

__device__ __forceinline__ u16 f2bf(float f) {
  union { float f; unsigned u; } v; v.f = f;
  unsigned r = v.u + 0x7FFFu + ((v.u >> 16) & 1u);   // round-to-nearest-even
  return (u16)(r >> 16);
}

__device__ __forceinline__ unsigned pkbf(float a, float b) {
  unsigned r;
  asm("v_cvt_pk_bf16_f32 %0, %1, %2" : "=v"(r) : "v"(a), "v"(b));
  return r;
}

__device__ __forceinline__ bf16x8 cvt8(float4 a, float4 b) {
  bf16x8 r;
  r[0] = (short)f2bf(a.x); r[1] = (short)f2bf(a.y);
  r[2] = (short)f2bf(a.z); r[3] = (short)f2bf(a.w);
  r[4] = (short)f2bf(b.x); r[5] = (short)f2bf(b.y);
  r[6] = (short)f2bf(b.z); r[7] = (short)f2bf(b.w);
  return r;
}

#define GLDS(SRC, DST) __builtin_amdgcn_global_load_lds( \
    (const __attribute__((address_space(1))) unsigned int*)(SRC), \
    (__attribute__((address_space(3))) unsigned int*)(DST), 16, 0, 0)

// ---- prep: W image in MFMA-fragment order + G image (bf16) ------------------
// W image: ws[ty*65536 + c*8192 + o*32 + kl]  (u16), kl = k&31, c = k>>5.
__global__ __launch_bounds__(256)
void prep_kernel(const float* __restrict__ w, const float* __restrict__ G,
                 u16* __restrict__ ws)
{
  int e = blockIdx.x * 256 + threadIdx.x;
  if (e < N_TYPE * D_OUT * D_IN) {
    int ty = e >> 16, o = (e >> 8) & 255, k = e & 255;
    int c = k >> 5, kl = k & 31;
    ws[(size_t)ty * 65536 + c * 8192 + o * 32 + kl] = f2bf(w[e]);
  } else if (e < N_TYPE * D_OUT * D_IN + N_NODE * N_NODE) {
    int g = e - N_TYPE * D_OUT * D_IN;
    int m = g >> 6, n = g & 63;
    int s = (n >> 5) * 4 + ((n >> 2) & 3);
    int j = ((n >> 4) & 1) * 4 + (n & 3);
    ws[524288 + (size_t)(m * 8 + (s ^ (m & 7))) * 8 + j] = f2bf(G[g]);
  }
}

// ---- Kernel A: h[b][n][o] = sum_i W[type[n]][o][i] * x[b][n][i] -------------
// 64 batches x 256 out per block, one node; 8 waves (32 o-cols each).
// Round-8-proven one-barrier structure: x tile (64KB fp32) via global_load_lds,
// ONE __syncthreads, compute from LDS + L2-hot W image.
// vs round 8: 2x batches/block -> W L2-traffic halved (512->256MB), barriers
// halved; XCD-swizzled grid so each XCD owns contiguous btiles (x L2-exclusive).
__global__ __launch_bounds__(512, 4)
void pernode_gemm(const float* __restrict__ x, const u16* __restrict__ wimg,
                  const int* __restrict__ types, u16* __restrict__ hout)
{
  // bijective XCD swizzle: 2048 blocks, XCD k gets swz in [k*256,(k+1)*256)
  const int swz   = (blockIdx.x & 7) * 256 + (blockIdx.x >> 3);
  const int node  = swz & 63;
  const int btile = swz >> 6;
  const int b0 = btile * 64;
  const int t = threadIdx.x;
  const int lane = t & 63, wid = t >> 6;
  const int l15 = lane & 15, lk = lane >> 4;
  const int o0 = wid * 32;                    // wave's o-tile (2 frags)

  __shared__ alignas(16) float xs[64][256];   // 64KB; unit p of row r = src unit p^r

  const int ty = types[node];

  #pragma unroll
  for (int j = 0; j < 8; ++j) {
    const int r = wid * 8 + j;
    const float* src = x + ((size_t)(b0 + r) * N_NODE + node) * D_IN + ((lane ^ r) << 2);
    GLDS(src, &xs[r][0]);
  }
  __syncthreads();

  f32x4 acc[2][4];   // [mf: o-frag][nb: b-frag]
  #pragma unroll
  for (int i = 0; i < 2; ++i)
    #pragma unroll
    for (int j = 0; j < 4; ++j) acc[i][j] = (f32x4){0.f, 0.f, 0.f, 0.f};

  const u16* wbp = wimg + (size_t)ty * 65536 + (size_t)(o0 + l15) * 32 + lk * 8;

  #pragma unroll
  for (int c = 0; c < 8; ++c) {
    bf16x8 wf[2];
    #pragma unroll
    for (int mf = 0; mf < 2; ++mf)
      wf[mf] = *(const bf16x8*)(wbp + c * 8192 + mf * 512);
    bf16x8 xf[4];
    #pragma unroll
    for (int nb = 0; nb < 4; ++nb) {
      const int r = nb * 16 + l15;
      const int u0 = c * 8 + lk * 2;
      float4 lo = *(const float4*)&xs[r][((u0 ^ r) & 63) << 2];
      float4 hi = *(const float4*)&xs[r][(((u0 + 1) ^ r) & 63) << 2];
      xf[nb] = cvt8(lo, hi);
    }
    #pragma unroll
    for (int nb = 0; nb < 4; ++nb)
      #pragma unroll
      for (int mf = 0; mf < 2; ++mf)
        acc[mf][nb] = __builtin_amdgcn_mfma_f32_16x16x32_bf16(wf[mf], xf[nb], acc[mf][nb], 0, 0, 0);
  }

  // D frag: row(o) = o0 + mf*16 + lk*4 + rr (contiguous), col(b) = b0 + nb*16 + l15
  #pragma unroll
  for (int nb = 0; nb < 4; ++nb) {
    u16* hp = hout + (size_t)(b0 + nb * 16 + l15) * 32768 + node * 256 + o0 + lk * 4;
    #pragma unroll
    for (int mf = 0; mf < 2; ++mf) {
      uint2 pv = { pkbf(acc[mf][nb][0], acc[mf][nb][1]),
                   pkbf(acc[mf][nb][2], acc[mf][nb][3]) };
      *(uint2*)(hp + mf * 16) = pv;
    }
  }
}

// ---- Kernel B: out[b][m][o] = sum_n G[m][n]*h[b][n][o] + bias[o], MFMA, in-place
__global__ __launch_bounds__(256)
void graph_mix(const u16* __restrict__ gimg, const float* __restrict__ bias,
               float* __restrict__ out)
{
  const int b = blockIdx.x;
  const int t = threadIdx.x;
  const int lane = t & 63, wid = t >> 6, l15 = lane & 15, lk = lane >> 4;

  __shared__ u16 himg[16384];   // [n][o] bf16, linear
  __shared__ u16 gl[4096];      // G image (perm+swizzle baked by prep)

  const u16* hsrc = (const u16*)((const char*)out + (size_t)b * 65536);
  bf16x8 hv[8], gv[2];
  #pragma unroll
  for (int i = 0; i < 8; ++i) hv[i] = *(const bf16x8*)(hsrc + t * 64 + i * 8);
  #pragma unroll
  for (int i = 0; i < 2; ++i) gv[i] = *(const bf16x8*)(gimg + t * 16 + i * 8);
  float bb[4];
  #pragma unroll
  for (int nt = 0; nt < 4; ++nt) bb[nt] = bias[wid * 64 + nt * 16 + l15];
  #pragma unroll
  for (int i = 0; i < 8; ++i) *(bf16x8*)&himg[t * 64 + i * 8] = hv[i];
  #pragma unroll
  for (int i = 0; i < 2; ++i) *(bf16x8*)&gl[t * 16 + i * 8] = gv[i];
  __syncthreads();   // drains vmcnt: all global h reads complete before any out write

  f32x4 acc[4][4];
  #pragma unroll
  for (int i = 0; i < 4; ++i)
    #pragma unroll
    for (int j = 0; j < 4; ++j) acc[i][j] = (f32x4){0.f, 0.f, 0.f, 0.f};

  #pragma unroll
  for (int ks = 0; ks < 2; ++ks) {
    bf16x8 ag[4];
    #pragma unroll
    for (int mt = 0; mt < 4; ++mt) {
      int row = mt * 16 + l15;
      ag[mt] = *(const bf16x8*)&gl[(size_t)row * 64 + (size_t)((ks * 4 + lk) ^ (row & 7)) * 8];
    }
    #pragma unroll
    for (int nt = 0; nt < 4; ++nt) {
      int o = wid * 64 + nt * 16 + l15;
      bf16x8 bh;
      #pragma unroll
      for (int j = 0; j < 8; ++j) {   // gather h with the same k-perm as G's image
        int nk = ks * 32 + lk * 4 + (j & 3) + ((j >> 2) << 4);
        bh[j] = (short)himg[nk * 256 + o];
      }
      #pragma unroll
      for (int mt = 0; mt < 4; ++mt)
        acc[mt][nt] = __builtin_amdgcn_mfma_f32_16x16x32_bf16(ag[mt], bh, acc[mt][nt], 0, 0, 0);
    }
  }
  float* ob = out + (size_t)b * 16384;
  #pragma unroll
  for (int mt = 0; mt < 4; ++mt)
    #pragma unroll
    for (int nt = 0; nt < 4; ++nt)
      #pragma unroll
      for (int rr = 0; rr < 4; ++rr) {
        int m = mt * 16 + lk * 4 + rr;
        int o = wid * 64 + nt * 16 + l15;
        ob[(size_t)m * 256 + o] = acc[mt][nt][rr] + bb[nt];
      }
}

// ---- fallback (round-1, passing) — used only if ws_size is too small --------
__global__ __launch_bounds__(256)
void pernode_gemm_fb(const float* __restrict__ x, const float* __restrict__ w,
                     const int* __restrict__ types, float* __restrict__ h)
{
  const int node = blockIdx.y;
  const int b0   = blockIdx.x * 64;
  const int t    = threadIdx.x;
  const int lane = t & 63;
  const int wid  = t >> 6;
  const int wm   = wid >> 1;
  const int wn   = wid & 1;
  const int l15  = lane & 15;
  const int lk   = lane >> 4;

  __shared__ alignas(16) u16 xs[64][72];
  __shared__ alignas(16) u16 wsm[256][72];

  const int ty = types[node];
  const float* wb = w + (size_t)ty * (D_OUT * D_IN);
  const float* xb = x + ((size_t)b0 * N_NODE + node) * D_IN;

  f32x4 acc[2][8];
  #pragma unroll
  for (int i = 0; i < 2; ++i)
    #pragma unroll
    for (int j = 0; j < 8; ++j) acc[i][j] = (f32x4){0.f,0.f,0.f,0.f};

  const int cg = t & 15, r0 = t >> 4, c = cg * 4;
  const int dst = (c >> 5) * 32 + ((c >> 2) & 3) * 8 + ((c >> 4) & 1) * 4;

  for (int kc = 0; kc < 4; ++kc) {
    const int k0 = kc * 64;
    #pragma unroll
    for (int p = 0; p < 4; ++p) {
      const int row = r0 + p * 16;
      const float4 v = *(const float4*)(xb + (size_t)row * (N_NODE * D_IN) + k0 + c);
      ushort4 bv = { f2bf(v.x), f2bf(v.y), f2bf(v.z), f2bf(v.w) };
      *(ushort4*)&xs[row][dst] = bv;
    }
    #pragma unroll
    for (int p = 0; p < 16; ++p) {
      const int row = r0 + p * 16;
      const float4 v = *(const float4*)(wb + (size_t)row * D_IN + k0 + c);
      ushort4 bv = { f2bf(v.x), f2bf(v.y), f2bf(v.z), f2bf(v.w) };
      *(ushort4*)&wsm[row][dst] = bv;
    }
    __syncthreads();
    #pragma unroll
    for (int ks = 0; ks < 2; ++ks) {
      bf16x8 af[2], bfv[8];
      #pragma unroll
      for (int tm = 0; tm < 2; ++tm)
        af[tm] = *(const bf16x8*)&xs[wm*32 + tm*16 + l15][ks*32 + lk*8];
      #pragma unroll
      for (int tn = 0; tn < 8; ++tn)
        bfv[tn] = *(const bf16x8*)&wsm[wn*128 + tn*16 + l15][ks*32 + lk*8];
      #pragma unroll
      for (int tm = 0; tm < 2; ++tm)
        #pragma unroll
        for (int tn = 0; tn < 8; ++tn)
          acc[tm][tn] = __builtin_amdgcn_mfma_f32_16x16x32_bf16(af[tm], bfv[tn], acc[tm][tn], 0, 0, 0);
    }
    __syncthreads();
  }
  #pragma unroll
  for (int tm = 0; tm < 2; ++tm)
    #pragma unroll
    for (int tn = 0; tn < 8; ++tn)
      #pragma unroll
      for (int rr = 0; rr < 4; ++rr) {
        const int bb2 = b0 + wm*32 + tm*16 + lk*4 + rr;
        const int oo  = wn*128 + tn*16 + l15;
        h[((size_t)bb2 * N_NODE + node) * D_OUT + oo] = acc[tm][tn][rr];
      }
}

__global__ __launch_bounds__(256)
void graph_mix_fb(const float* __restrict__ G, const float* __restrict__ bias,
                  float* __restrict__ hb)
{
  const int b = blockIdx.x;
  const int t = threadIdx.x;
  float* base = hb + (size_t)b * (N_NODE * D_OUT);
  float hreg[N_NODE];
  #pragma unroll
  for (int n = 0; n < N_NODE; ++n) hreg[n] = base[(size_t)n * D_OUT + t];
  const float bv = bias[t];
  for (int m = 0; m < N_NODE; ++m) {
    const float* gr = G + m * N_NODE;
    float a0 = 0.f, a1 = 0.f, a2 = 0.f, a3 = 0.f;
    #pragma unroll
    for (int n = 0; n < N_NODE; n += 4) {
      a0 += gr[n]     * hreg[n];
      a1 += gr[n + 1] * hreg[n + 1];
      a2 += gr[n + 2] * hreg[n + 2];
      a3 += gr[n + 3] * hreg[n + 3];
    }
    base[(size_t)m * D_OUT + t] = (a0 + a1) + (a2 + a3) + bv;
  }
}

extern "C" void kernel_launch(void* const* d_in, const int* in_sizes, int n_in,
                              void* d_out, int out_size, void* d_ws, size_t ws_size,
                              hipStream_t stream) {
  const float* x     = (const float*)d_in[0];
  const float* G     = (const float*)d_in[1];
  const float* w     = (const float*)d_in[2];
  const float* bias  = (const float*)d_in[3];
  const int*   types = (const int*)d_in[4];

  const size_t WS_NEED = (size_t)(524288 + 4096) * 2;   // W img 1MB + G img 8KB
  if (ws_size >= WS_NEED) {
    u16* ws = (u16*)d_ws;
    prep_kernel<<<2064, 256, 0, stream>>>(w, G, ws);
    pernode_gemm<<<2048, 512, 0, stream>>>(x, ws, types, (u16*)d_out);
    graph_mix<<<2048, 256, 0, stream>>>(ws + 524288, bias, (float*)d_out);
  } else {
    dim3 gA(B_TOT / 64, N_NODE);
    pernode_gemm_fb<<<gA, 256, 0, stream>>>(x, w, types, (float*)d_out);
    graph_mix_fb<<<B_TOT, 256, 0, stream>>>(G, bias, (float*)d_out);
  }
}

// Round 11
// 94.438 us; speedup vs baseline: 1.0503x; 1.0177x over previous
//
#include <hip/hip_runtime.h>
#include <hip/hip_bf16.h>
#include <cstdint>

#define B_TOT  2048
#define N_NODE 64
#define D_IN   256
#define D_OUT  256
#define N_TYPE 8

typedef __attribute__((ext_vector_type(8))) short bf16x8;
typedef __attribute__((ext_vector_type(4))) float f32x4;
typedef unsigned short u16;

__device__ __forceinline__ u16 f2bf(float f) {
  union { float f; unsigned u; } v; v.f = f;
  unsigned r = v.u + 0x7FFFu + ((v.u >> 16) & 1u);   // round-to-nearest-even
  return (u16)(r >> 16);
}

__device__ __forceinline__ unsigned pkbf(float a, float b) {
  unsigned r;
  asm("v_cvt_pk_bf16_f32 %0, %1, %2" : "=v"(r) : "v"(a), "v"(b));
  return r;
}

// pkbf-based x-conversion (A/B vs r9's manual f2bf cvt8 — only change this round)
__device__ __forceinline__ bf16x8 pack8(float4 a, float4 b) {
  union { unsigned u[4]; bf16x8 v; } r;
  r.u[0] = pkbf(a.x, a.y);
  r.u[1] = pkbf(a.z, a.w);
  r.u[2] = pkbf(b.x, b.y);
  r.u[3] = pkbf(b.z, b.w);
  return r.v;
}

#define GLDS(SRC, DST) __builtin_amdgcn_global_load_lds( \
    (const __attribute__((address_space(1))) unsigned int*)(SRC), \
    (__attribute__((address_space(3))) unsigned int*)(DST), 16, 0, 0)

// ---- prep: W image in MFMA-fragment order + G image (bf16) ------------------
// W image: ws[ty*65536 + c*8192 + o*32 + kl]  (u16), kl = k&31, c = k>>5.
__global__ __launch_bounds__(256)
void prep_kernel(const float* __restrict__ w, const float* __restrict__ G,
                 u16* __restrict__ ws)
{
  int e = blockIdx.x * 256 + threadIdx.x;
  if (e < N_TYPE * D_OUT * D_IN) {
    int ty = e >> 16, o = (e >> 8) & 255, k = e & 255;
    int c = k >> 5, kl = k & 31;
    ws[(size_t)ty * 65536 + c * 8192 + o * 32 + kl] = f2bf(w[e]);
  } else if (e < N_TYPE * D_OUT * D_IN + N_NODE * N_NODE) {
    int g = e - N_TYPE * D_OUT * D_IN;
    int m = g >> 6, n = g & 63;
    int s = (n >> 5) * 4 + ((n >> 2) & 3);
    int j = ((n >> 4) & 1) * 4 + (n & 3);
    ws[524288 + (size_t)(m * 8 + (s ^ (m & 7))) * 8 + j] = f2bf(G[g]);
  }
}

// ---- Kernel A: h[b][n][o] = sum_i W[type[n]][o][i] * x[b][n][i] -------------
// r9-proven structure (64 batches x 256 out, 8 waves, one GLDS stage + ONE
// __syncthreads, compute from LDS + L2-hot W image, XCD-swizzled grid).
// ONLY change vs r9: x bf16 conversion uses v_cvt_pk_bf16_f32 (pack8).
__global__ __launch_bounds__(512, 4)
void pernode_gemm(const float* __restrict__ x, const u16* __restrict__ wimg,
                  const int* __restrict__ types, u16* __restrict__ hout)
{
  // bijective XCD swizzle: 2048 blocks, XCD k gets swz in [k*256,(k+1)*256)
  const int swz   = (blockIdx.x & 7) * 256 + (blockIdx.x >> 3);
  const int node  = swz & 63;
  const int btile = swz >> 6;
  const int b0 = btile * 64;
  const int t = threadIdx.x;
  const int lane = t & 63, wid = t >> 6;
  const int l15 = lane & 15, lk = lane >> 4;
  const int o0 = wid * 32;                    // wave's o-tile (2 frags)

  __shared__ alignas(16) float xs[64][256];   // 64KB; unit p of row r = src unit p^r

  const int ty = types[node];

  #pragma unroll
  for (int j = 0; j < 8; ++j) {
    const int r = wid * 8 + j;
    const float* src = x + ((size_t)(b0 + r) * N_NODE + node) * D_IN + ((lane ^ r) << 2);
    GLDS(src, &xs[r][0]);
  }
  __syncthreads();

  f32x4 acc[2][4];   // [mf: o-frag][nb: b-frag]
  #pragma unroll
  for (int i = 0; i < 2; ++i)
    #pragma unroll
    for (int j = 0; j < 4; ++j) acc[i][j] = (f32x4){0.f, 0.f, 0.f, 0.f};

  const u16* wbp = wimg + (size_t)ty * 65536 + (size_t)(o0 + l15) * 32 + lk * 8;

  #pragma unroll
  for (int c = 0; c < 8; ++c) {
    bf16x8 wf[2];
    #pragma unroll
    for (int mf = 0; mf < 2; ++mf)
      wf[mf] = *(const bf16x8*)(wbp + c * 8192 + mf * 512);
    bf16x8 xf[4];
    #pragma unroll
    for (int nb = 0; nb < 4; ++nb) {
      const int r = nb * 16 + l15;
      const int u0 = c * 8 + lk * 2;
      float4 lo = *(const float4*)&xs[r][((u0 ^ r) & 63) << 2];
      float4 hi = *(const float4*)&xs[r][(((u0 + 1) ^ r) & 63) << 2];
      xf[nb] = pack8(lo, hi);
    }
    #pragma unroll
    for (int nb = 0; nb < 4; ++nb)
      #pragma unroll
      for (int mf = 0; mf < 2; ++mf)
        acc[mf][nb] = __builtin_amdgcn_mfma_f32_16x16x32_bf16(wf[mf], xf[nb], acc[mf][nb], 0, 0, 0);
  }

  // D frag: row(o) = o0 + mf*16 + lk*4 + rr (contiguous), col(b) = b0 + nb*16 + l15
  #pragma unroll
  for (int nb = 0; nb < 4; ++nb) {
    u16* hp = hout + (size_t)(b0 + nb * 16 + l15) * 32768 + node * 256 + o0 + lk * 4;
    #pragma unroll
    for (int mf = 0; mf < 2; ++mf) {
      uint2 pv = { pkbf(acc[mf][nb][0], acc[mf][nb][1]),
                   pkbf(acc[mf][nb][2], acc[mf][nb][3]) };
      *(uint2*)(hp + mf * 16) = pv;
    }
  }
}

// ---- Kernel B: out[b][m][o] = sum_n G[m][n]*h[b][n][o] + bias[o], MFMA, in-place
__global__ __launch_bounds__(256)
void graph_mix(const u16* __restrict__ gimg, const float* __restrict__ bias,
               float* __restrict__ out)
{
  const int b = blockIdx.x;
  const int t = threadIdx.x;
  const int lane = t & 63, wid = t >> 6, l15 = lane & 15, lk = lane >> 4;

  __shared__ u16 himg[16384];   // [n][o] bf16, linear
  __shared__ u16 gl[4096];      // G image (perm+swizzle baked by prep)

  const u16* hsrc = (const u16*)((const char*)out + (size_t)b * 65536);
  bf16x8 hv[8], gv[2];
  #pragma unroll
  for (int i = 0; i < 8; ++i) hv[i] = *(const bf16x8*)(hsrc + t * 64 + i * 8);
  #pragma unroll
  for (int i = 0; i < 2; ++i) gv[i] = *(const bf16x8*)(gimg + t * 16 + i * 8);
  float bb[4];
  #pragma unroll
  for (int nt = 0; nt < 4; ++nt) bb[nt] = bias[wid * 64 + nt * 16 + l15];
  #pragma unroll
  for (int i = 0; i < 8; ++i) *(bf16x8*)&himg[t * 64 + i * 8] = hv[i];
  #pragma unroll
  for (int i = 0; i < 2; ++i) *(bf16x8*)&gl[t * 16 + i * 8] = gv[i];
  __syncthreads();   // drains vmcnt: all global h reads complete before any out write

  f32x4 acc[4][4];
  #pragma unroll
  for (int i = 0; i < 4; ++i)
    #pragma unroll
    for (int j = 0; j < 4; ++j) acc[i][j] = (f32x4){0.f, 0.f, 0.f, 0.f};

  #pragma unroll
  for (int ks = 0; ks < 2; ++ks) {
    bf16x8 ag[4];
    #pragma unroll
    for (int mt = 0; mt < 4; ++mt) {
      int row = mt * 16 + l15;
      ag[mt] = *(const bf16x8*)&gl[(size_t)row * 64 + (size_t)((ks * 4 + lk) ^ (row & 7)) * 8];
    }
    #pragma unroll
    for (int nt = 0; nt < 4; ++nt) {
      int o = wid * 64 + nt * 16 + l15;
      bf16x8 bh;
      #pragma unroll
      for (int j = 0; j < 8; ++j) {   // gather h with the same k-perm as G's image
        int nk = ks * 32 + lk * 4 + (j & 3) + ((j >> 2) << 4);
        bh[j] = (short)himg[nk * 256 + o];
      }
      #pragma unroll
      for (int mt = 0; mt < 4; ++mt)
        acc[mt][nt] = __builtin_amdgcn_mfma_f32_16x16x32_bf16(ag[mt], bh, acc[mt][nt], 0, 0, 0);
    }
  }
  float* ob = out + (size_t)b * 16384;
  #pragma unroll
  for (int mt = 0; mt < 4; ++mt)
    #pragma unroll
    for (int nt = 0; nt < 4; ++nt)
      #pragma unroll
      for (int rr = 0; rr < 4; ++rr) {
        int m = mt * 16 + lk * 4 + rr;
        int o = wid * 64 + nt * 16 + l15;
        ob[(size_t)m * 256 + o] = acc[mt][nt][rr] + bb[nt];
      }
}

// ---- fallback (round-1, passing) — used only if ws_size is too small --------
__global__ __launch_bounds__(256)
void pernode_gemm_fb(const float* __restrict__ x, const float* __restrict__ w,
                     const int* __restrict__ types, float* __restrict__ h)
{
  const int node = blockIdx.y;
  const int b0   = blockIdx.x * 64;
  const int t    = threadIdx.x;
  const int lane = t & 63;
  const int wid  = t >> 6;
  const int wm   = wid >> 1;
  const int wn   = wid & 1;
  const int l15  = lane & 15;
  const int lk   = lane >> 4;

  __shared__ alignas(16) u16 xs[64][72];
  __shared__ alignas(16) u16 wsm[256][72];

  const int ty = types[node];
  const float* wb = w + (size_t)ty * (D_OUT * D_IN);
  const float* xb = x + ((size_t)b0 * N_NODE + node) * D_IN;

  f32x4 acc[2][8];
  #pragma unroll
  for (int i = 0; i < 2; ++i)
    #pragma unroll
    for (int j = 0; j < 8; ++j) acc[i][j] = (f32x4){0.f,0.f,0.f,0.f};

  const int cg = t & 15, r0 = t >> 4, c = cg * 4;
  const int dst = (c >> 5) * 32 + ((c >> 2) & 3) * 8 + ((c >> 4) & 1) * 4;

  for (int kc = 0; kc < 4; ++kc) {
    const int k0 = kc * 64;
    #pragma unroll
    for (int p = 0; p < 4; ++p) {
      const int row = r0 + p * 16;
      const float4 v = *(const float4*)(xb + (size_t)row * (N_NODE * D_IN) + k0 + c);
      ushort4 bv = { f2bf(v.x), f2bf(v.y), f2bf(v.z), f2bf(v.w) };
      *(ushort4*)&xs[row][dst] = bv;
    }
    #pragma unroll
    for (int p = 0; p < 16; ++p) {
      const int row = r0 + p * 16;
      const float4 v = *(const float4*)(wb + (size_t)row * D_IN + k0 + c);
      ushort4 bv = { f2bf(v.x), f2bf(v.y), f2bf(v.z), f2bf(v.w) };
      *(ushort4*)&wsm[row][dst] = bv;
    }
    __syncthreads();
    #pragma unroll
    for (int ks = 0; ks < 2; ++ks) {
      bf16x8 af[2], bfv[8];
      #pragma unroll
      for (int tm = 0; tm < 2; ++tm)
        af[tm] = *(const bf16x8*)&xs[wm*32 + tm*16 + l15][ks*32 + lk*8];
      #pragma unroll
      for (int tn = 0; tn < 8; ++tn)
        bfv[tn] = *(const bf16x8*)&wsm[wn*128 + tn*16 + l15][ks*32 + lk*8];
      #pragma unroll
      for (int tm = 0; tm < 2; ++tm)
        #pragma unroll
        for (int tn = 0; tn < 8; ++tn)
          acc[tm][tn] = __builtin_amdgcn_mfma_f32_16x16x32_bf16(af[tm], bfv[tn], acc[tm][tn], 0, 0, 0);
    }
    __syncthreads();
  }
  #pragma unroll
  for (int tm = 0; tm < 2; ++tm)
    #pragma unroll
    for (int tn = 0; tn < 8; ++tn)
      #pragma unroll
      for (int rr = 0; rr < 4; ++rr) {
        const int bb2 = b0 + wm*32 + tm*16 + lk*4 + rr;
        const int oo  = wn*128 + tn*16 + l15;
        h[((size_t)bb2 * N_NODE + node) * D_OUT + oo] = acc[tm][tn][rr];
      }
}

__global__ __launch_bounds__(256)
void graph_mix_fb(const float* __restrict__ G, const float* __restrict__ bias,
                  float* __restrict__ hb)
{
  const int b = blockIdx.x;
  const int t = threadIdx.x;
  float* base = hb + (size_t)b * (N_NODE * D_OUT);
  float hreg[N_NODE];
  #pragma unroll
  for (int n = 0; n < N_NODE; ++n) hreg[n] = base[(size_t)n * D_OUT + t];
  const float bv = bias[t];
  for (int m = 0; m < N_NODE; ++m) {
    const float* gr = G + m * N_NODE;
    float a0 = 0.f, a1 = 0.f, a2 = 0.f, a3 = 0.f;
    #pragma unroll
    for (int n = 0; n < N_NODE; n += 4) {
      a0 += gr[n]     * hreg[n];
      a1 += gr[n + 1] * hreg[n + 1];
      a2 += gr[n + 2] * hreg[n + 2];
      a3 += gr[n + 3] * hreg[n + 3];
    }
    base[(size_t)m * D_OUT + t] = (a0 + a1) + (a2 + a3) + bv;
  }
}

extern "C" void kernel_launch(void* const* d_in, const int* in_sizes, int n_in,
                              void* d_out, int out_size, void* d_ws, size_t ws_size,
                              hipStream_t stream) {
  const float* x     = (const float*)d_in[0];
  const float* G     = (const float*)d_in[1];
  const float* w     = (const float*)d_in[2];
  const float* bias  = (const float*)d_in[3];
  const int*   types = (const int*)d_in[4];

  const size_t WS_NEED = (size_t)(524288 + 4096) * 2;   // W img 1MB + G img 8KB
  if (ws_size >= WS_NEED) {
    u16* ws = (u16*)d_ws;
    prep_kernel<<<2064, 256, 0, stream>>>(w, G, ws);
    pernode_gemm<<<2048, 512, 0, stream>>>(x, ws, types, (u16*)d_out);
    graph_mix<<<2048, 256, 0, stream>>>(ws + 524288, bias, (float*)d_out);
  } else {
    dim3 gA(B_TOT / 64, N_NODE);
    pernode_gemm_fb<<<gA, 256, 0, stream>>>(x, w, types, (float*)d_out);
    graph_mix_fb<<<B_TOT, 256, 0, stream>>>(G, bias, (float*)d_out);
  }
}

// Round 15
// 94.014 us; speedup vs baseline: 1.0550x; 1.0045x over previous
//
#include <hip/hip_runtime.h>
#include <hip/hip_bf16.h>
#include <cstdint>

#define B_TOT  2048
#define N_NODE 64
#define D_IN   256
#define D_OUT  256
#define N_TYPE 8

typedef __attribute__((ext_vector_type(8))) short bf16x8;
typedef __attribute__((ext_vector_type(4))) float f32x4;
typedef unsigned short u16;

__device__ __forceinline__ u16 f2bf(float f) {
  union { float f; unsigned u; } v; v.f = f;
  unsigned r = v.u + 0x7FFFu + ((v.u >> 16) & 1u);   // round-to-nearest-even
  return (u16)(r >> 16);
}

__device__ __forceinline__ unsigned pkbf(float a, float b) {
  unsigned r;
  asm("v_cvt_pk_bf16_f32 %0, %1, %2" : "=v"(r) : "v"(a), "v"(b));
  return r;
}

__device__ __forceinline__ bf16x8 pack8(float4 a, float4 b) {
  union { unsigned u[4]; bf16x8 v; } r;
  r.u[0] = pkbf(a.x, a.y);
  r.u[1] = pkbf(a.z, a.w);
  r.u[2] = pkbf(b.x, b.y);
  r.u[3] = pkbf(b.z, b.w);
  return r.v;
}

#define GLDS(SRC, DST) __builtin_amdgcn_global_load_lds( \
    (const __attribute__((address_space(1))) unsigned int*)(SRC), \
    (__attribute__((address_space(3))) unsigned int*)(DST), 16, 0, 0)

// ---- prep: W image in MFMA-fragment order + G image (bf16) ------------------
// W image: ws[ty*65536 + c*8192 + o*32 + kl]  (u16), kl = k&31, c = k>>5.
__global__ __launch_bounds__(256)
void prep_kernel(const float* __restrict__ w, const float* __restrict__ G,
                 u16* __restrict__ ws)
{
  int e = blockIdx.x * 256 + threadIdx.x;
  if (e < N_TYPE * D_OUT * D_IN) {
    int ty = e >> 16, o = (e >> 8) & 255, k = e & 255;
    int c = k >> 5, kl = k & 31;
    ws[(size_t)ty * 65536 + c * 8192 + o * 32 + kl] = f2bf(w[e]);
  } else if (e < N_TYPE * D_OUT * D_IN + N_NODE * N_NODE) {
    int g = e - N_TYPE * D_OUT * D_IN;
    int m = g >> 6, n = g & 63;
    int s = (n >> 5) * 4 + ((n >> 2) & 3);
    int j = ((n >> 4) & 1) * 4 + (n & 3);
    ws[524288 + (size_t)(m * 8 + (s ^ (m & 7))) * 8 + j] = f2bf(G[g]);
  }
}

// ---- Kernel A: h[b][n][o] = sum_i W[type[n]][o][i] * x[b][n][i] -------------
// Proven skeleton (r4/r8/r9/r11): 64 batches x 256 out per block, one node;
// 8 waves; x tile staged fp32 via global_load_lds; ONE __syncthreads; compute
// from LDS + L2-hot W image; pack8 (v_cvt_pk) conversion; XCD-swizzled grid.
__global__ __launch_bounds__(512, 4)
void pernode_gemm(const float* __restrict__ x, const u16* __restrict__ wimg,
                  const int* __restrict__ types, u16* __restrict__ hout)
{
  // bijective XCD swizzle: 2048 blocks, XCD k gets swz in [k*256,(k+1)*256)
  const int swz   = (blockIdx.x & 7) * 256 + (blockIdx.x >> 3);
  const int node  = swz & 63;
  const int btile = swz >> 6;
  const int b0 = btile * 64;
  const int t = threadIdx.x;
  const int lane = t & 63, wid = t >> 6;
  const int l15 = lane & 15, lk = lane >> 4;
  const int o0 = wid * 32;                    // wave's o-tile (2 frags)

  __shared__ alignas(16) float xs[64][256];   // 64KB; unit p of row r = src unit p^r

  const int ty = types[node];

  #pragma unroll
  for (int j = 0; j < 8; ++j) {
    const int r = wid * 8 + j;
    const float* src = x + ((size_t)(b0 + r) * N_NODE + node) * D_IN + ((lane ^ r) << 2);
    GLDS(src, &xs[r][0]);
  }
  __syncthreads();

  f32x4 acc[2][4];   // [mf: o-frag][nb: b-frag]
  #pragma unroll
  for (int i = 0; i < 2; ++i)
    #pragma unroll
    for (int j = 0; j < 4; ++j) acc[i][j] = (f32x4){0.f, 0.f, 0.f, 0.f};

  const u16* wbp = wimg + (size_t)ty * 65536 + (size_t)(o0 + l15) * 32 + lk * 8;

  #pragma unroll
  for (int c = 0; c < 8; ++c) {
    bf16x8 wf[2];
    #pragma unroll
    for (int mf = 0; mf < 2; ++mf)
      wf[mf] = *(const bf16x8*)(wbp + c * 8192 + mf * 512);
    bf16x8 xf[4];
    #pragma unroll
    for (int nb = 0; nb < 4; ++nb) {
      const int r = nb * 16 + l15;
      const int u0 = c * 8 + lk * 2;
      float4 lo = *(const float4*)&xs[r][((u0 ^ r) & 63) << 2];
      float4 hi = *(const float4*)&xs[r][(((u0 + 1) ^ r) & 63) << 2];
      xf[nb] = pack8(lo, hi);
    }
    #pragma unroll
    for (int nb = 0; nb < 4; ++nb)
      #pragma unroll
      for (int mf = 0; mf < 2; ++mf)
        acc[mf][nb] = __builtin_amdgcn_mfma_f32_16x16x32_bf16(wf[mf], xf[nb], acc[mf][nb], 0, 0, 0);
  }

  // D frag: row(o) = o0 + mf*16 + lk*4 + rr (contiguous), col(b) = b0 + nb*16 + l15
  #pragma unroll
  for (int nb = 0; nb < 4; ++nb) {
    u16* hp = hout + (size_t)(b0 + nb * 16 + l15) * 32768 + node * 256 + o0 + lk * 4;
    #pragma unroll
    for (int mf = 0; mf < 2; ++mf) {
      uint2 pv = { pkbf(acc[mf][nb][0], acc[mf][nb][1]),
                   pkbf(acc[mf][nb][2], acc[mf][nb][3]) };
      *(uint2*)(hp + mf * 16) = pv;
    }
  }
}

// ---- Kernel B: out[b][m][o] = sum_n G[m][n]*h[b][n][o] + bias[o], MFMA, in-place
__global__ __launch_bounds__(256)
void graph_mix(const u16* __restrict__ gimg, const float* __restrict__ bias,
               float* __restrict__ out)
{
  const int b = blockIdx.x;
  const int t = threadIdx.x;
  const int lane = t & 63, wid = t >> 6, l15 = lane & 15, lk = lane >> 4;

  __shared__ u16 himg[16384];   // [n][o] bf16, linear
  __shared__ u16 gl[4096];      // G image (perm+swizzle baked by prep)

  const u16* hsrc = (const u16*)((const char*)out + (size_t)b * 65536);
  bf16x8 hv[8], gv[2];
  #pragma unroll
  for (int i = 0; i < 8; ++i) hv[i] = *(const bf16x8*)(hsrc + t * 64 + i * 8);
  #pragma unroll
  for (int i = 0; i < 2; ++i) gv[i] = *(const bf16x8*)(gimg + t * 16 + i * 8);
  float bb[4];
  #pragma unroll
  for (int nt = 0; nt < 4; ++nt) bb[nt] = bias[wid * 64 + nt * 16 + l15];
  #pragma unroll
  for (int i = 0; i < 8; ++i) *(bf16x8*)&himg[t * 64 + i * 8] = hv[i];
  #pragma unroll
  for (int i = 0; i < 2; ++i) *(bf16x8*)&gl[t * 16 + i * 8] = gv[i];
  __syncthreads();   // drains vmcnt: all global h reads complete before any out write

  f32x4 acc[4][4];
  #pragma unroll
  for (int i = 0; i < 4; ++i)
    #pragma unroll
    for (int j = 0; j < 4; ++j) acc[i][j] = (f32x4){0.f, 0.f, 0.f, 0.f};

  #pragma unroll
  for (int ks = 0; ks < 2; ++ks) {
    bf16x8 ag[4];
    #pragma unroll
    for (int mt = 0; mt < 4; ++mt) {
      int row = mt * 16 + l15;
      ag[mt] = *(const bf16x8*)&gl[(size_t)row * 64 + (size_t)((ks * 4 + lk) ^ (row & 7)) * 8];
    }
    #pragma unroll
    for (int nt = 0; nt < 4; ++nt) {
      int o = wid * 64 + nt * 16 + l15;
      bf16x8 bh;
      #pragma unroll
      for (int j = 0; j < 8; ++j) {   // gather h with the same k-perm as G's image
        int nk = ks * 32 + lk * 4 + (j & 3) + ((j >> 2) << 4);
        bh[j] = (short)himg[nk * 256 + o];
      }
      #pragma unroll
      for (int mt = 0; mt < 4; ++mt)
        acc[mt][nt] = __builtin_amdgcn_mfma_f32_16x16x32_bf16(ag[mt], bh, acc[mt][nt], 0, 0, 0);
    }
  }
  float* ob = out + (size_t)b * 16384;
  #pragma unroll
  for (int mt = 0; mt < 4; ++mt)
    #pragma unroll
    for (int nt = 0; nt < 4; ++nt)
      #pragma unroll
      for (int rr = 0; rr < 4; ++rr) {
        int m = mt * 16 + lk * 4 + rr;
        int o = wid * 64 + nt * 16 + l15;
        ob[(size_t)m * 256 + o] = acc[mt][nt][rr] + bb[nt];
      }
}

// ---- fallback (round-1, passing) — used only if ws_size is too small --------
__global__ __launch_bounds__(256)
void pernode_gemm_fb(const float* __restrict__ x, const float* __restrict__ w,
                     const int* __restrict__ types, float* __restrict__ h)
{
  const int node = blockIdx.y;
  const int b0   = blockIdx.x * 64;
  const int t    = threadIdx.x;
  const int lane = t & 63;
  const int wid  = t >> 6;
  const int wm   = wid >> 1;
  const int wn   = wid & 1;
  const int l15  = lane & 15;
  const int lk   = lane >> 4;

  __shared__ alignas(16) u16 xs[64][72];
  __shared__ alignas(16) u16 wsm[256][72];

  const int ty = types[node];
  const float* wb = w + (size_t)ty * (D_OUT * D_IN);
  const float* xb = x + ((size_t)b0 * N_NODE + node) * D_IN;

  f32x4 acc[2][8];
  #pragma unroll
  for (int i = 0; i < 2; ++i)
    #pragma unroll
    for (int j = 0; j < 8; ++j) acc[i][j] = (f32x4){0.f,0.f,0.f,0.f};

  const int cg = t & 15, r0 = t >> 4, c = cg * 4;
  const int dst = (c >> 5) * 32 + ((c >> 2) & 3) * 8 + ((c >> 4) & 1) * 4;

  for (int kc = 0; kc < 4; ++kc) {
    const int k0 = kc * 64;
    #pragma unroll
    for (int p = 0; p < 4; ++p) {
      const int row = r0 + p * 16;
      const float4 v = *(const float4*)(xb + (size_t)row * (N_NODE * D_IN) + k0 + c);
      ushort4 bv = { f2bf(v.x), f2bf(v.y), f2bf(v.z), f2bf(v.w) };
      *(ushort4*)&xs[row][dst] = bv;
    }
    #pragma unroll
    for (int p = 0; p < 16; ++p) {
      const int row = r0 + p * 16;
      const float4 v = *(const float4*)(wb + (size_t)row * D_IN + k0 + c);
      ushort4 bv = { f2bf(v.x), f2bf(v.y), f2bf(v.z), f2bf(v.w) };
      *(ushort4*)&wsm[row][dst] = bv;
    }
    __syncthreads();
    #pragma unroll
    for (int ks = 0; ks < 2; ++ks) {
      bf16x8 af[2], bfv[8];
      #pragma unroll
      for (int tm = 0; tm < 2; ++tm)
        af[tm] = *(const bf16x8*)&xs[wm*32 + tm*16 + l15][ks*32 + lk*8];
      #pragma unroll
      for (int tn = 0; tn < 8; ++tn)
        bfv[tn] = *(const bf16x8*)&wsm[wn*128 + tn*16 + l15][ks*32 + lk*8];
      #pragma unroll
      for (int tm = 0; tm < 2; ++tm)
        #pragma unroll
        for (int tn = 0; tn < 8; ++tn)
          acc[tm][tn] = __builtin_amdgcn_mfma_f32_16x16x32_bf16(af[tm], bfv[tn], acc[tm][tn], 0, 0, 0);
    }
    __syncthreads();
  }
  #pragma unroll
  for (int tm = 0; tm < 2; ++tm)
    #pragma unroll
    for (int tn = 0; tn < 8; ++tn)
      #pragma unroll
      for (int rr = 0; rr < 4; ++rr) {
        const int bb2 = b0 + wm*32 + tm*16 + lk*4 + rr;
        const int oo  = wn*128 + tn*16 + l15;
        h[((size_t)bb2 * N_NODE + node) * D_OUT + oo] = acc[tm][tn][rr];
      }
}

__global__ __launch_bounds__(256)
void graph_mix_fb(const float* __restrict__ G, const float* __restrict__ bias,
                  float* __restrict__ hb)
{
  const int b = blockIdx.x;
  const int t = threadIdx.x;
  float* base = hb + (size_t)b * (N_NODE * D_OUT);
  float hreg[N_NODE];
  #pragma unroll
  for (int n = 0; n < N_NODE; ++n) hreg[n] = base[(size_t)n * D_OUT + t];
  const float bv = bias[t];
  for (int m = 0; m < N_NODE; ++m) {
    const float* gr = G + m * N_NODE;
    float a0 = 0.f, a1 = 0.f, a2 = 0.f, a3 = 0.f;
    #pragma unroll
    for (int n = 0; n < N_NODE; n += 4) {
      a0 += gr[n]     * hreg[n];
      a1 += gr[n + 1] * hreg[n + 1];
      a2 += gr[n + 2] * hreg[n + 2];
      a3 += gr[n + 3] * hreg[n + 3];
    }
    base[(size_t)m * D_OUT + t] = (a0 + a1) + (a2 + a3) + bv;
  }
}

extern "C" void kernel_launch(void* const* d_in, const int* in_sizes, int n_in,
                              void* d_out, int out_size, void* d_ws, size_t ws_size,
                              hipStream_t stream) {
  const float* x     = (const float*)d_in[0];
  const float* G     = (const float*)d_in[1];
  const float* w     = (const float*)d_in[2];
  const float* bias  = (const float*)d_in[3];
  const int*   types = (const int*)d_in[4];

  const size_t WS_NEED = (size_t)(524288 + 4096) * 2;   // W img 1MB + G img 8KB
  if (ws_size >= WS_NEED) {
    u16* ws = (u16*)d_ws;
    prep_kernel<<<2064, 256, 0, stream>>>(w, G, ws);
    pernode_gemm<<<2048, 512, 0, stream>>>(x, ws, types, (u16*)d_out);
    graph_mix<<<2048, 256, 0, stream>>>(ws + 524288, bias, (float*)d_out);
  } else {
    dim3 gA(B_TOT / 64, N_NODE);
    pernode_gemm_fb<<<gA, 256, 0, stream>>>(x, w, types, (float*)d_out);
    graph_mix_fb<<<B_TOT, 256, 0, stream>>>(G, bias, (float*)d_out);
  }
}